// Round 3
// baseline (406.214 us; speedup 1.0000x reference)
//
#include <hip/hip_runtime.h>

#define BN 8192

typedef __attribute__((ext_vector_type(8))) __bf16 bf16x8;
typedef __attribute__((ext_vector_type(4))) float float4v;
typedef float4v __attribute__((aligned(4))) float4a;   // 4B-aligned vector store
typedef __attribute__((ext_vector_type(4))) int int4v;

__device__ inline unsigned short f2bf(float f) {
  union { float f; unsigned u; } v;
  v.f = f;
  unsigned r = v.u + 0x7FFFu + ((v.u >> 16) & 1u);
  return (unsigned short)(r >> 16);
}

// Kernel 1: per-row reciprocal L2 norms (fp32) + fp32->bf16 pack of A and B.
__global__ __launch_bounds__(256) void prep_kernel(
    const float* __restrict__ fa, const float* __restrict__ fb,
    unsigned short* __restrict__ abf, unsigned short* __restrict__ bbf,
    float* __restrict__ rna, float* __restrict__ rnb) {
  const int wave = threadIdx.x >> 6, lane = threadIdx.x & 63;
  const int w = blockIdx.x * 4 + wave;
  const int mat = w >> 13;            // 0 = A, 1 = B
  const int row = w & (BN - 1);
  const float* src = mat ? fb : fa;
  unsigned short* dst = mat ? bbf : abf;
  float* nrm = mat ? rnb : rna;
  const float2 v = ((const float2*)src)[row * 64 + lane];
  float s = v.x * v.x + v.y * v.y;
#pragma unroll
  for (int m = 32; m >= 1; m >>= 1) s += __shfl_xor(s, m, 64);
  ushort2 h;
  h.x = f2bf(v.x);
  h.y = f2bf(v.y);
  ((ushort2*)dst)[row * 64 + lane] = h;
  if (lane == 0) nrm[row] = 1.0f / sqrtf(s);  // norms ~sqrt(128); eps clamp vacuous
}

// Kernel 2: 128x128 tile of cos = (A @ B^T) * rna * rnb, bf16 MFMA.
// SWAPPED-OPERAND epilogue: mfma(B_frag, A_frag) puts 4 consecutive C COLUMNS
// in each lane's 4 acc registers (row = i*16+lcol, col = j*16+quad*4+r), so C
// is stored straight from registers as float4 — no LDS transpose, no epilogue
// barriers. Wave store = 16 rows x 64B contiguous. The global +1-dword shift
// is handled by aligned(4) vector stores (gfx9+ HW supports unaligned).
// Row E/S sums: per-lane accumulate + 2-step cross-quad shfl_xor.
__global__ __launch_bounds__(256, 4) void gemm_kernel(
    const unsigned short* __restrict__ abf, const unsigned short* __restrict__ bbf,
    const float* __restrict__ rna, const float* __restrict__ rnb,
    const int* __restrict__ lab,
    float* __restrict__ out,            // out[0]=loss, out+1 = cos[8192][8192]
    float* __restrict__ lrow, float* __restrict__ srow) {
  __shared__ int labr[128], labc[128];
  __shared__ float rnaS[128], rnbS[128];

  const int tid = threadIdx.x;
  const int wave = tid >> 6, lane = tid & 63;
  const int quad = lane >> 4, lcol = lane & 15;
  const int bx = blockIdx.x, by = blockIdx.y;

  if (tid < 128) {
    labr[tid] = lab[by * 128 + tid];
    rnaS[tid] = rna[by * 128 + tid];
  } else {
    labc[tid - 128] = lab[bx * 128 + (tid - 128)];
    rnbS[tid - 128] = rnb[bx * 128 + (tid - 128)];
  }

  const int m0 = (wave >> 1) * 64;   // wave's local row base
  const int n0 = (wave & 1) * 64;    // wave's local col base

  // Fragment bases: lane (quad,lcol) holds row lcol(+i*16), k = kb*32+quad*8..+7
  const unsigned short* pa = abf + (size_t)(by * 128 + m0 + lcol) * 128 + quad * 8;
  const unsigned short* pb = bbf + (size_t)(bx * 128 + n0 + lcol) * 128 + quad * 8;

  float4v acc[4][4];
#pragma unroll
  for (int i = 0; i < 4; ++i)
#pragma unroll
    for (int j = 0; j < 4; ++j) acc[i][j] = float4v{0.f, 0.f, 0.f, 0.f};

#pragma unroll 1   // keep frag live-range = one kb step (reg budget for 4 blocks/CU)
  for (int kb = 0; kb < 4; ++kb) {
    bf16x8 af[4], bfr[4];
#pragma unroll
    for (int i = 0; i < 4; ++i) {
      af[i]  = *(const bf16x8*)(pa + (size_t)i * 2048 + kb * 32);
      bfr[i] = *(const bf16x8*)(pb + (size_t)i * 2048 + kb * 32);
    }
    // Swapped operands: acc[i][j][r] = C[m0+i*16+lcol][n0+j*16+quad*4+r]
#pragma unroll
    for (int i = 0; i < 4; ++i)
#pragma unroll
      for (int j = 0; j < 4; ++j)
        acc[i][j] = __builtin_amdgcn_mfma_f32_16x16x32_bf16(bfr[j], af[i], acc[i][j], 0, 0, 0);
  }

  __syncthreads();   // labr/labc/rnaS/rnbS ready

  // Per-thread column-side constants: cols n0 + j*16 + quad*4 + r
  float rnbv[16];
  int labcv[16];
#pragma unroll
  for (int j = 0; j < 4; ++j) {
    const float4v t = *(const float4v*)&rnbS[n0 + j * 16 + quad * 4];
    const int4v lt = *(const int4v*)&labc[n0 + j * 16 + quad * 4];
#pragma unroll
    for (int r = 0; r < 4; ++r) { rnbv[4 * j + r] = t[r]; labcv[4 * j + r] = lt[r]; }
  }

#pragma unroll
  for (int i = 0; i < 4; ++i) {
    const int row = m0 + i * 16 + lcol;          // this lane's C row
    const float rnav = rnaS[row];
    const int labrv = labr[row];
    float accE = 0.f, accS = 0.f;
    float* rp = out + 1 + ((size_t)(by * 128 + row) << 13) + bx * 128 + n0 + quad * 4;
#pragma unroll
    for (int j = 0; j < 4; ++j) {
      float4v v;
#pragma unroll
      for (int r = 0; r < 4; ++r) {
        const float cv = acc[i][j][r] * rnav * rnbv[4 * j + r];
        v[r] = cv;
        accE += __expf(cv - 1.0f);
        if (labrv == labcv[4 * j + r]) accS += cv;
      }
      __builtin_nontemporal_store(v, (float4a*)(rp + j * 16));
    }
    // Reduce across the 4 quads (same lcol = same row, disjoint col subsets)
    accE += __shfl_xor(accE, 16, 64);
    accE += __shfl_xor(accE, 32, 64);
    accS += __shfl_xor(accS, 16, 64);
    accS += __shfl_xor(accS, 32, 64);
    if (quad == 0) {
      atomicAdd(&lrow[by * 128 + row], accE);
      atomicAdd(&srow[by * 128 + row], accS);
    }
  }
}

// Kernel 3: loss = -sum_i [S_i - C_i*(1 + log l_i)] / B^2, single block.
// C_i = hist[label_i] (exact count, no need to accumulate in gemm).
__global__ __launch_bounds__(1024) void loss_kernel(
    const int* __restrict__ lab, const float* __restrict__ lrow,
    const float* __restrict__ srow, float* __restrict__ out) {
  __shared__ int hist[2048];
  __shared__ float red[1024];
  for (int i = threadIdx.x; i < 2048; i += 1024) hist[i] = 0;
  __syncthreads();
  for (int i = threadIdx.x; i < BN; i += 1024) atomicAdd(&hist[lab[i]], 1);
  __syncthreads();
  float p = 0.f;
  for (int i = threadIdx.x; i < BN; i += 1024)
    p += srow[i] - (float)hist[lab[i]] * (1.0f + __logf(lrow[i]));
  red[threadIdx.x] = p;
  __syncthreads();
  for (int s = 512; s >= 1; s >>= 1) {
    if (threadIdx.x < s) red[threadIdx.x] += red[threadIdx.x + s];
    __syncthreads();
  }
  if (threadIdx.x == 0) out[0] = -red[0] / 67108864.0f;  // B*B = 2^26 exact
}

extern "C" void kernel_launch(void* const* d_in, const int* in_sizes, int n_in,
                              void* d_out, int out_size, void* d_ws, size_t ws_size,
                              hipStream_t stream) {
  const int* lab = (const int*)d_in[0];
  const float* fa = (const float*)d_in[1];
  const float* fb = (const float*)d_in[2];
  float* out = (float*)d_out;

  char* ws = (char*)d_ws;
  unsigned short* abf = (unsigned short*)ws;                          // 2 MB
  unsigned short* bbf = (unsigned short*)(ws + (2u << 20));           // 2 MB
  float* rna  = (float*)(ws + (4u << 20));                            // 32 KB
  float* rnb  = (float*)(ws + (4u << 20) + 32768);                    // 32 KB
  float* lrow = (float*)(ws + (4u << 20) + 2 * 32768);                // 32 KB
  float* srow = (float*)(ws + (4u << 20) + 3 * 32768);                // 32 KB

  hipMemsetAsync(ws + (4u << 20) + 2 * 32768, 0, 2 * 32768, stream);

  prep_kernel<<<4096, 256, 0, stream>>>(fa, fb, abf, bbf, rna, rnb);
  gemm_kernel<<<dim3(64, 64), 256, 0, stream>>>(abf, bbf, rna, rnb, lab, out,
                                                lrow, srow);
  loss_kernel<<<1, 1024, 0, stream>>>(lab, lrow, srow, out);
}